// Round 8
// baseline (455.564 us; speedup 1.0000x reference)
//
#include <hip/hip_runtime.h>
#include <stdint.h>

#define D_DIM 128
#define K_DIM 1024
#define BM 64
#define N_TOTAL 262144
#define MAXF 16384
#define RR 8

// Fold (log2 e)^2 into the squared-distance scale so exp(-dist) = exp2(-sqrt(SIGMA*d2))
// with no per-element multiply. sqrt(SIGMA)*ln2 == 1 exactly recovers dist for the loss.
// Numerically validated R1-R6 (absmax = 0.0).
#define SIGMA 2.0813689810056077f      // (log2 e)^2
#define NS2   (-2.0f * SIGMA)
#define TAUS  (0.1f * SIGMA)           // TAU rescaled into SIGMA*d2 space
#define LN2   0.69314718055994531f

#if __has_builtin(__builtin_amdgcn_exp2f)
#define EXP2F __builtin_amdgcn_exp2f
#else
#define EXP2F exp2f
#endif

typedef __attribute__((ext_vector_type(8))) short short8;
typedef __attribute__((ext_vector_type(4))) float f32x4;

__device__ __forceinline__ unsigned short f2bf(float f) {
    union { float f; uint32_t u; } v; v.f = f;
    uint32_t r = v.u + 0x7fffu + ((v.u >> 16) & 1u);
    return (unsigned short)(r >> 16);
}
__device__ __forceinline__ float bf2f(unsigned short h) {
    union { float f; uint32_t u; } v; v.u = ((uint32_t)h) << 16;
    return v.f;
}

// ---------------------------------------------------------------------------
// prep: merged prep_frag (blocks 0..127) + prep_c2 (blocks 128..131).
// Per-thread arithmetic is BIT-IDENTICAL to the previously validated separate
// kernels (c2 rounding feeds refine's exactness — do not alter). Saves one
// kernel launch from the tail.
// ---------------------------------------------------------------------------
__global__ void prep_kernel(const float* __restrict__ C,
                            unsigned short* __restrict__ Cfrag,
                            float* __restrict__ c2) {
    const int tid = threadIdx.x;
    if (blockIdx.x < 128) {
        int g = blockIdx.x * 256 + tid;   // 0..32767
        int col = g >> 5;
        int dq = g & 31;
        float4 v = ((const float4*)C)[g];
        unsigned short h0 = f2bf(v.x), h1 = f2bf(v.y), h2 = f2bf(v.z), h3 = f2bf(v.w);
        unsigned short l0 = f2bf(v.x - bf2f(h0)), l1 = f2bf(v.y - bf2f(h1));
        unsigned short l2 = f2bf(v.z - bf2f(h2)), l3 = f2bf(v.w - bf2f(h3));
        int ntg = col >> 4;
        int cl = col & 15;
        int d0 = dq << 2;
        int ds = d0 >> 5;
        int lane = (((d0 >> 3) & 3) << 4) | cl;
        int jb = d0 & 7;
        size_t idx = (((size_t)(ntg * 4 + ds) * 64 + lane) * 8 + jb);
        uint2 hv = make_uint2((uint32_t)h0 | ((uint32_t)h1 << 16),
                              (uint32_t)h2 | ((uint32_t)h3 << 16));
        uint2 lv = make_uint2((uint32_t)l0 | ((uint32_t)l1 << 16),
                              (uint32_t)l2 | ((uint32_t)l3 << 16));
        *(uint2*)&Cfrag[idx] = hv;
        *(uint2*)&Cfrag[131072 + idx] = lv;
    } else {
        int col = (blockIdx.x - 128) * 256 + tid;   // 0..1023
        const float4* C4 = (const float4*)(C + (size_t)col * D_DIM);
        float s0 = 0.f, s1 = 0.f, s2 = 0.f, s3 = 0.f;
        #pragma unroll
        for (int dq = 0; dq < 32; ++dq) {
            float4 v = C4[dq];
            s0 = fmaf(v.x, v.x, s0);
            s1 = fmaf(v.y, v.y, s1);
            s2 = fmaf(v.z, v.z, s2);
            s3 = fmaf(v.w, v.w, s3);
        }
        c2[col] = (s0 + s1) + (s2 + s3);
    }
}

// ---------------------------------------------------------------------------
// fused: bf16x3 MFMA distances + packed-key argmin/2nd-min + sum exp(-d) + loss
// R4/R6-measured base (281.7 us, VGPR 84, no spill, 3 blocks/CU): 16 chunks x
// 64 cols, acc 16 AGPR, __launch_bounds__(256,3).
// R7: cross-iteration B-prefetch — the ds=0 B-frags of chunk kc+1 (4 x 16B
// from L2, +16 VGPR) are issued BEFORE chunk kc's epilogue, giving them ~400
// cyc of VALU slack instead of ~60 cyc. Targets the ~50% issue-idle (exposed
// L2 latency at 3 waves/SIMD). Spill tripwire: FETCH_SIZE > 90 MB => revert.
// R5 falsified setprio here (do not re-add); R1/R2 falsified min_waves with
// bigger live sets (even-split VGPR/AGPR budget).
// ---------------------------------------------------------------------------
__global__ __launch_bounds__(256, 3) void fused_mfma_kernel(
        const float* __restrict__ E,
        const unsigned short* __restrict__ Cfrag,
        const float* __restrict__ c2g,
        float* __restrict__ out,
        int* __restrict__ fcnt,
        int* __restrict__ flist)
{
    __shared__ unsigned short Elds[32 * 528];   // 33 KB frag-layout E hi/lo
    __shared__ float c2s[K_DIM];                // 4 KB (SIGMA-scaled)
    __shared__ float e2s[BM];                   // 256 B (raw |e|^2)
    __shared__ uint32_t mrgk[BM * 2];
    __shared__ uint32_t mrgm[BM * 2];
    __shared__ float    mrgs[BM * 2];

    const int tid = threadIdx.x;
    const int lane = tid & 63;
    const int w = tid >> 6;
    const int Rh = w >> 1;       // row half (32 rows each)
    const int Nh = w & 1;        // col half of each 64-col chunk (32 cols)
    const int q = lane >> 4;
    const int mcol = lane & 15;
    const int row0 = blockIdx.x * BM;

    for (int i = tid; i < K_DIM; i += 256) c2s[i] = SIGMA * c2g[i];

    // ---- stage E tile: fp32 -> bf16 hi/lo frag layout; e2 via shuffle ----
    {
        const float4* E4 = (const float4*)(E + (size_t)row0 * D_DIM);
        #pragma unroll
        for (int it = 0; it < 8; ++it) {
            int chunk = it * 256 + tid;      // 0..2047
            int r = chunk >> 5;              // row 0..63
            int dq = chunk & 31;
            float4 v = E4[chunk];
            float p = fmaf(v.x, v.x, fmaf(v.y, v.y, fmaf(v.z, v.z, v.w * v.w)));
            // 32 consecutive lanes share row r -> xor-reduce within the group
            #pragma unroll
            for (int off = 1; off < 32; off <<= 1) p += __shfl_xor(p, off);
            if ((tid & 31) == 0) e2s[r] = p;
            unsigned short h0 = f2bf(v.x), h1 = f2bf(v.y), h2 = f2bf(v.z), h3 = f2bf(v.w);
            unsigned short l0 = f2bf(v.x - bf2f(h0)), l1 = f2bf(v.y - bf2f(h1));
            unsigned short l2 = f2bf(v.z - bf2f(h2)), l3 = f2bf(v.w - bf2f(h3));
            int d0 = dq << 2;
            int mt = r >> 4;
            int ds = d0 >> 5;
            int lane_slot = (((d0 >> 3) & 3) << 4) | (r & 15);
            int jb = d0 & 7;
            int segh = (mt * 4 + ds) * 528 + lane_slot * 8 + jb;
            uint2 hv = make_uint2((uint32_t)h0 | ((uint32_t)h1 << 16),
                                  (uint32_t)h2 | ((uint32_t)h3 << 16));
            uint2 lv = make_uint2((uint32_t)l0 | ((uint32_t)l1 << 16),
                                  (uint32_t)l2 | ((uint32_t)l3 << 16));
            *(uint2*)&Elds[segh] = hv;
            *(uint2*)&Elds[16 * 528 + segh] = lv;
        }
    }
    __syncthreads();

    // per-lane SIGMA*e2 for the 8 owned rows
    float e2rs[8];
    #pragma unroll
    for (int s = 0; s < 8; ++s)
        e2rs[s] = SIGMA * e2s[(Rh * 2 + (s >> 2)) * 16 + q * 4 + (s & 3)];

    uint32_t k1v[8], m2v[8];
    float sv[8];
    #pragma unroll
    for (int s = 0; s < 8; ++s) { k1v[s] = 0xFFFFFFFFu; m2v[s] = 0xFFFFFFFFu; sv[s] = 0.f; }

    const short8* Bfrag = (const short8*)Cfrag;   // hi at [0], lo at +16384 (short8 units)

    // prefetch ds=0 B-frags for kc=0
    short8 pbh[2], pbl[2];
    #pragma unroll
    for (int ni = 0; ni < 2; ++ni) {
        size_t bidx = ((size_t)(Nh * 2 + ni) * 4) * 64 + lane;
        pbh[ni] = Bfrag[bidx];
        pbl[ni] = Bfrag[16384 + bidx];
    }

    #pragma unroll 1
    for (int kc = 0; kc < 16; ++kc) {            // 16 chunks x 64 cols
        f32x4 acc[2][2];
        #pragma unroll
        for (int i = 0; i < 2; ++i)
            #pragma unroll
            for (int j = 0; j < 2; ++j)
                acc[i][j] = (f32x4){0.f, 0.f, 0.f, 0.f};

        #pragma unroll
        for (int ds = 0; ds < 4; ++ds) {
            short8 ah[2], al[2];
            #pragma unroll
            for (int mi = 0; mi < 2; ++mi) {
                int seg = ((Rh * 2 + mi) * 4 + ds) * 528 + lane * 8;
                ah[mi] = *(const short8*)&Elds[seg];
                al[mi] = *(const short8*)&Elds[16 * 528 + seg];
            }
            #pragma unroll
            for (int ni = 0; ni < 2; ++ni) {
                short8 bh, bl;
                if (ds == 0) {                   // compile-time branch (unrolled)
                    bh = pbh[ni];
                    bl = pbl[ni];
                } else {
                    int ntg = kc * 4 + Nh * 2 + ni;
                    size_t bidx = ((size_t)ntg * 4 + ds) * 64 + lane;
                    bh = Bfrag[bidx];
                    bl = Bfrag[16384 + bidx];
                }
                #pragma unroll
                for (int mi = 0; mi < 2; ++mi) {
                    acc[mi][ni] = __builtin_amdgcn_mfma_f32_16x16x32_bf16(al[mi], bh, acc[mi][ni], 0, 0, 0);
                    acc[mi][ni] = __builtin_amdgcn_mfma_f32_16x16x32_bf16(ah[mi], bl, acc[mi][ni], 0, 0, 0);
                    acc[mi][ni] = __builtin_amdgcn_mfma_f32_16x16x32_bf16(ah[mi], bh, acc[mi][ni], 0, 0, 0);
                }
            }
        }

        // prefetch next chunk's ds=0 B-frags: in flight across the epilogue
        if (kc < 15) {
            #pragma unroll
            for (int ni = 0; ni < 2; ++ni) {
                size_t bidx = ((size_t)((kc + 1) * 4 + Nh * 2 + ni) * 4) * 64 + lane;
                pbh[ni] = Bfrag[bidx];
                pbl[ni] = Bfrag[16384 + bidx];
            }
        }

        // fused epilogue for this 64-col chunk (SIGMA-scaled d2; validated math)
        #pragma unroll
        for (int ni = 0; ni < 2; ++ni) {
            int kidx = kc * 64 + Nh * 32 + ni * 16 + mcol;
            float c2v = c2s[kidx];
            #pragma unroll
            for (int mi = 0; mi < 2; ++mi) {
                #pragma unroll
                for (int r = 0; r < 4; ++r) {
                    int s = mi * 4 + r;
                    float d2 = fmaf(NS2, acc[mi][ni][r], e2rs[s] + c2v);
                    uint32_t key = (__float_as_uint(d2) & 0xFFFFFC00u) | (uint32_t)kidx;
                    float dist = __builtin_amdgcn_sqrtf(__builtin_fabsf(d2));
                    sv[s] += EXP2F(-dist);
                    uint32_t k1 = k1v[s];
                    m2v[s] = min(m2v[s], max(k1, key));
                    k1v[s] = min(k1, key);
                }
            }
        }
    }

    // ---- merge across the 16 lanes sharing q (cols) ----
    #pragma unroll
    for (int s = 0; s < 8; ++s) {
        #pragma unroll
        for (int off = 1; off < 16; off <<= 1) {
            uint32_t ok1 = __shfl_xor(k1v[s], off);
            uint32_t om2 = __shfl_xor(m2v[s], off);
            float osv = __shfl_xor(sv[s], off);
            m2v[s] = min(min(m2v[s], om2), max(k1v[s], ok1));
            k1v[s] = min(k1v[s], ok1);
            sv[s] += osv;
        }
    }
    if (mcol == 0) {
        #pragma unroll
        for (int s = 0; s < 8; ++s) {
            int row = (Rh * 2 + (s >> 2)) * 16 + q * 4 + (s & 3);
            mrgk[row * 2 + Nh] = k1v[s];
            mrgm[row * 2 + Nh] = m2v[s];
            mrgs[row * 2 + Nh] = sv[s];
        }
    }
    __syncthreads();

    // ---- final per-row merge across the two col-halves; outputs ----
    if (tid < BM) {
        uint32_t ka = mrgk[tid * 2 + 0], kb = mrgk[tid * 2 + 1];
        uint32_t ma = mrgm[tid * 2 + 0], mb = mrgm[tid * 2 + 1];
        float ss = mrgs[tid * 2 + 0] + mrgs[tid * 2 + 1];
        uint32_t k1 = min(ka, kb);
        uint32_t m2 = min(min(ma, mb), max(ka, kb));
        float m1q = __uint_as_float(k1 & 0xFFFFFC00u);
        float m2q = __uint_as_float(m2 & 0xFFFFFC00u);
        int i1 = (int)(k1 & 1023u);
        // m1q is SIGMA*d2min (quantized); sqrt(SIGMA)*ln2 == 1 recovers dist
        float lossr = logf(ss) + sqrtf(m1q) * LN2;
        out[1 + row0 + tid] = (float)i1;
        if (m2q - m1q < TAUS) {
            int idx = atomicAdd(fcnt, 1);
            if (idx < MAXF) flist[idx] = row0 + tid;
        }
        float v = lossr;
        #pragma unroll
        for (int off = 32; off > 0; off >>= 1) v += __shfl_down(v, off);
        if (tid == 0) atomicAdd(out, v * (1.0f / (float)N_TOTAL));
    }
}

// ---------------------------------------------------------------------------
// refine: exact fp32 recompute (precise sqrt, first-occurrence argmin) for
// flagged rows. EXACT R3/R6-measured version (best tail): RR=8, k-outer loop.
// R4 (RR=16) regressed; R5 (dq-outer) was within noise but not better — keep
// this one. Tie semantics: min by (dist, then lower k) == packed u64 min.
// ---------------------------------------------------------------------------
__global__ void refine_kernel(const float* __restrict__ E,
                              const float* __restrict__ C,
                              const float* __restrict__ c2g,
                              const int* __restrict__ fcnt,
                              const int* __restrict__ flist,
                              float* __restrict__ out) {
    int cnt = *fcnt;
    if (cnt > MAXF) cnt = MAXF;
    int base = blockIdx.x * RR;
    if (base >= cnt) return;

    __shared__ float Er[RR][D_DIM];          // 4 KB
    __shared__ float e2r_[RR];
    __shared__ int rowid[RR];
    __shared__ unsigned long long wred[RR][4];

    const int tid = threadIdx.x;
    if (tid < RR) {
        int rr = base + tid;
        if (rr >= cnt) rr = cnt - 1;         // duplicate last row: benign rewrite
        rowid[tid] = flist[rr];
    }
    __syncthreads();
    for (int i = tid; i < RR * 32; i += 256) {
        int rr = i >> 5, dq = i & 31;
        ((float4*)Er[rr])[dq] = ((const float4*)(E + (size_t)rowid[rr] * D_DIM))[dq];
    }
    __syncthreads();
    if (tid < RR) {
        float s = 0.f;
        for (int d = 0; d < D_DIM; ++d) s = fmaf(Er[tid][d], Er[tid][d], s);
        e2r_[tid] = s;
    }
    __syncthreads();

    unsigned long long best[RR];
    #pragma unroll
    for (int r = 0; r < RR; ++r) best[r] = ~0ull;

    for (int ii = 0; ii < 4; ++ii) {
        int k = ii * 256 + tid;
        const float4* C4 = (const float4*)(C + (size_t)k * D_DIM);
        float dot[RR];
        #pragma unroll
        for (int r = 0; r < RR; ++r) dot[r] = 0.f;
        for (int dq = 0; dq < 32; ++dq) {
            float4 cv = C4[dq];
            int d0 = dq * 4;
            #pragma unroll
            for (int r = 0; r < RR; ++r) {
                dot[r] = fmaf(Er[r][d0], cv.x,
                          fmaf(Er[r][d0 + 1], cv.y,
                           fmaf(Er[r][d0 + 2], cv.z,
                            fmaf(Er[r][d0 + 3], cv.w, dot[r]))));
            }
        }
        float c2v = c2g[k];
        #pragma unroll
        for (int r = 0; r < RR; ++r) {
            float d2 = (e2r_[r] + c2v) - 2.f * dot[r];
            float dist = sqrtf(fmaxf(d2, 0.f));
            unsigned long long key =
                (((unsigned long long)__float_as_uint(dist)) << 10) | (unsigned)k;
            best[r] = best[r] < key ? best[r] : key;
        }
    }

    const int wv = tid >> 6;
    #pragma unroll
    for (int r = 0; r < RR; ++r) {
        unsigned long long b = best[r];
        #pragma unroll
        for (int off = 32; off > 0; off >>= 1) {
            unsigned long long o = __shfl_xor(b, off);
            b = o < b ? o : b;
        }
        if ((tid & 63) == 0) wred[r][wv] = b;
    }
    __syncthreads();
    if (tid < RR) {
        unsigned long long b = wred[tid][0];
        #pragma unroll
        for (int j = 1; j < 4; ++j) b = wred[tid][j] < b ? wred[tid][j] : b;
        out[1 + rowid[tid]] = (float)(int)(b & 1023u);
    }
}

extern "C" void kernel_launch(void* const* d_in, const int* in_sizes, int n_in,
                              void* d_out, int out_size, void* d_ws, size_t ws_size,
                              hipStream_t stream) {
    const float* E = (const float*)d_in[0];
    const float* C = (const float*)d_in[1];
    float* out = (float*)d_out;

    unsigned short* Cfrag = (unsigned short*)d_ws;                 // 512 KB
    float* c2 = (float*)((char*)d_ws + 524288);                    // 4 KB
    int* fcnt = (int*)((char*)d_ws + 524288 + 4096);               // 4 B
    int* flist = fcnt + 1;                                         // MAXF ints

    hipMemsetAsync(d_out, 0, sizeof(float), stream);   // loss accumulator
    hipMemsetAsync(fcnt, 0, sizeof(int), stream);      // refinement counter

    prep_kernel<<<dim3(132), dim3(256), 0, stream>>>(C, Cfrag, c2);
    fused_mfma_kernel<<<dim3(N_TOTAL / BM), dim3(256), 0, stream>>>(E, Cfrag, c2, out, fcnt, flist);
    refine_kernel<<<dim3(MAXF / RR), dim3(256), 0, stream>>>(E, C, c2, fcnt, flist, out);
}

// Round 9
// 438.571 us; speedup vs baseline: 1.0387x; 1.0387x over previous
//
#include <hip/hip_runtime.h>
#include <stdint.h>

#define D_DIM 128
#define K_DIM 1024
#define BM 64
#define N_TOTAL 262144
#define MAXF 16384
#define RR 8

// Fold (log2 e)^2 into the squared-distance scale so exp(-dist) = exp2(-sqrt(SIGMA*d2))
// with no per-element multiply. sqrt(SIGMA)*ln2 == 1 exactly recovers dist for the loss.
// Numerically validated R1-R8 (absmax = 0.0).
#define SIGMA 2.0813689810056077f      // (log2 e)^2
#define NS2   (-2.0f * SIGMA)
// Refine-flag threshold in SIGMA*d2 space. Safety bound: escapes need
// TAUS <= quant_step(0.0625 for sig*d2<1024) + 2*eps(bf16x3 ~3e-4) = 0.0631.
// All per-row minima have sig*d2 < 1024 (chi^2_128 tails), so 0.10 is 1.58x
// that bound. R0-R8 ran 0.208 (3.3x) — flags ~2x more rows than needed.
#define TAUS  0.10f
#define LN2   0.69314718055994531f

#if __has_builtin(__builtin_amdgcn_exp2f)
#define EXP2F __builtin_amdgcn_exp2f
#else
#define EXP2F exp2f
#endif

typedef __attribute__((ext_vector_type(8))) short short8;
typedef __attribute__((ext_vector_type(4))) float f32x4;

__device__ __forceinline__ unsigned short f2bf(float f) {
    union { float f; uint32_t u; } v; v.f = f;
    uint32_t r = v.u + 0x7fffu + ((v.u >> 16) & 1u);
    return (unsigned short)(r >> 16);
}
__device__ __forceinline__ float bf2f(unsigned short h) {
    union { float f; uint32_t u; } v; v.u = ((uint32_t)h) << 16;
    return v.f;
}

// ---------------------------------------------------------------------------
// prep: merged prep_frag (blocks 0..127) + prep_c2 (blocks 128..131).
// Block 128 additionally zeroes the loss accumulator and flag counter
// (replaces two hipMemsetAsync dispatches; stream order guarantees
// completion before fused_mfma_kernel). Per-thread c2/frag arithmetic is
// BIT-IDENTICAL to the validated kernels (c2 rounding feeds refine).
// ---------------------------------------------------------------------------
__global__ void prep_kernel(const float* __restrict__ C,
                            unsigned short* __restrict__ Cfrag,
                            float* __restrict__ c2,
                            float* __restrict__ out,
                            int* __restrict__ fcnt) {
    const int tid = threadIdx.x;
    if (blockIdx.x < 128) {
        int g = blockIdx.x * 256 + tid;   // 0..32767
        int col = g >> 5;
        int dq = g & 31;
        float4 v = ((const float4*)C)[g];
        unsigned short h0 = f2bf(v.x), h1 = f2bf(v.y), h2 = f2bf(v.z), h3 = f2bf(v.w);
        unsigned short l0 = f2bf(v.x - bf2f(h0)), l1 = f2bf(v.y - bf2f(h1));
        unsigned short l2 = f2bf(v.z - bf2f(h2)), l3 = f2bf(v.w - bf2f(h3));
        int ntg = col >> 4;
        int cl = col & 15;
        int d0 = dq << 2;
        int ds = d0 >> 5;
        int lane = (((d0 >> 3) & 3) << 4) | cl;
        int jb = d0 & 7;
        size_t idx = (((size_t)(ntg * 4 + ds) * 64 + lane) * 8 + jb);
        uint2 hv = make_uint2((uint32_t)h0 | ((uint32_t)h1 << 16),
                              (uint32_t)h2 | ((uint32_t)h3 << 16));
        uint2 lv = make_uint2((uint32_t)l0 | ((uint32_t)l1 << 16),
                              (uint32_t)l2 | ((uint32_t)l3 << 16));
        *(uint2*)&Cfrag[idx] = hv;
        *(uint2*)&Cfrag[131072 + idx] = lv;
    } else {
        if (blockIdx.x == 128 && tid == 0) {
            out[0] = 0.f;        // loss accumulator
            fcnt[0] = 0;         // refinement counter
        }
        int col = (blockIdx.x - 128) * 256 + tid;   // 0..1023
        const float4* C4 = (const float4*)(C + (size_t)col * D_DIM);
        float s0 = 0.f, s1 = 0.f, s2 = 0.f, s3 = 0.f;
        #pragma unroll
        for (int dq = 0; dq < 32; ++dq) {
            float4 v = C4[dq];
            s0 = fmaf(v.x, v.x, s0);
            s1 = fmaf(v.y, v.y, s1);
            s2 = fmaf(v.z, v.z, s2);
            s3 = fmaf(v.w, v.w, s3);
        }
        c2[col] = (s0 + s1) + (s2 + s3);
    }
}

// ---------------------------------------------------------------------------
// fused: bf16x3 MFMA distances + packed-key argmin/2nd-min + sum exp(-d) + loss
// EXACT R4/R6-measured structure (281.7 us, VGPR 84, no spill, 3 blocks/CU):
// 16 chunks x 64 cols, acc 16 AGPR, __launch_bounds__(256,3).
// Falsified — do not re-add: setprio (R5, -35us: starves the longer epilogue
// phase), min_waves>=3 with fat live set (R1/R2: even-split VGPR/AGPR budget
// spills), explicit B-prefetch (R8, +9us: constrains the scheduler, which
// already hoists the independent B-loads).
// ---------------------------------------------------------------------------
__global__ __launch_bounds__(256, 3) void fused_mfma_kernel(
        const float* __restrict__ E,
        const unsigned short* __restrict__ Cfrag,
        const float* __restrict__ c2g,
        float* __restrict__ out,
        int* __restrict__ fcnt,
        int* __restrict__ flist)
{
    __shared__ unsigned short Elds[32 * 528];   // 33 KB frag-layout E hi/lo
    __shared__ float c2s[K_DIM];                // 4 KB (SIGMA-scaled)
    __shared__ float e2s[BM];                   // 256 B (raw |e|^2)
    __shared__ uint32_t mrgk[BM * 2];
    __shared__ uint32_t mrgm[BM * 2];
    __shared__ float    mrgs[BM * 2];

    const int tid = threadIdx.x;
    const int lane = tid & 63;
    const int w = tid >> 6;
    const int Rh = w >> 1;       // row half (32 rows each)
    const int Nh = w & 1;        // col half of each 64-col chunk (32 cols)
    const int q = lane >> 4;
    const int mcol = lane & 15;
    const int row0 = blockIdx.x * BM;

    for (int i = tid; i < K_DIM; i += 256) c2s[i] = SIGMA * c2g[i];

    // ---- stage E tile: fp32 -> bf16 hi/lo frag layout; e2 via shuffle ----
    {
        const float4* E4 = (const float4*)(E + (size_t)row0 * D_DIM);
        #pragma unroll
        for (int it = 0; it < 8; ++it) {
            int chunk = it * 256 + tid;      // 0..2047
            int r = chunk >> 5;              // row 0..63
            int dq = chunk & 31;
            float4 v = E4[chunk];
            float p = fmaf(v.x, v.x, fmaf(v.y, v.y, fmaf(v.z, v.z, v.w * v.w)));
            // 32 consecutive lanes share row r -> xor-reduce within the group
            #pragma unroll
            for (int off = 1; off < 32; off <<= 1) p += __shfl_xor(p, off);
            if ((tid & 31) == 0) e2s[r] = p;
            unsigned short h0 = f2bf(v.x), h1 = f2bf(v.y), h2 = f2bf(v.z), h3 = f2bf(v.w);
            unsigned short l0 = f2bf(v.x - bf2f(h0)), l1 = f2bf(v.y - bf2f(h1));
            unsigned short l2 = f2bf(v.z - bf2f(h2)), l3 = f2bf(v.w - bf2f(h3));
            int d0 = dq << 2;
            int mt = r >> 4;
            int ds = d0 >> 5;
            int lane_slot = (((d0 >> 3) & 3) << 4) | (r & 15);
            int jb = d0 & 7;
            int segh = (mt * 4 + ds) * 528 + lane_slot * 8 + jb;
            uint2 hv = make_uint2((uint32_t)h0 | ((uint32_t)h1 << 16),
                                  (uint32_t)h2 | ((uint32_t)h3 << 16));
            uint2 lv = make_uint2((uint32_t)l0 | ((uint32_t)l1 << 16),
                                  (uint32_t)l2 | ((uint32_t)l3 << 16));
            *(uint2*)&Elds[segh] = hv;
            *(uint2*)&Elds[16 * 528 + segh] = lv;
        }
    }
    __syncthreads();

    // per-lane SIGMA*e2 for the 8 owned rows
    float e2rs[8];
    #pragma unroll
    for (int s = 0; s < 8; ++s)
        e2rs[s] = SIGMA * e2s[(Rh * 2 + (s >> 2)) * 16 + q * 4 + (s & 3)];

    uint32_t k1v[8], m2v[8];
    float sv[8];
    #pragma unroll
    for (int s = 0; s < 8; ++s) { k1v[s] = 0xFFFFFFFFu; m2v[s] = 0xFFFFFFFFu; sv[s] = 0.f; }

    const short8* Bfrag = (const short8*)Cfrag;   // hi at [0], lo at +16384 (short8 units)

    #pragma unroll 1
    for (int kc = 0; kc < 16; ++kc) {            // 16 chunks x 64 cols
        f32x4 acc[2][2];
        #pragma unroll
        for (int i = 0; i < 2; ++i)
            #pragma unroll
            for (int j = 0; j < 2; ++j)
                acc[i][j] = (f32x4){0.f, 0.f, 0.f, 0.f};

        #pragma unroll
        for (int ds = 0; ds < 4; ++ds) {
            short8 ah[2], al[2];
            #pragma unroll
            for (int mi = 0; mi < 2; ++mi) {
                int seg = ((Rh * 2 + mi) * 4 + ds) * 528 + lane * 8;
                ah[mi] = *(const short8*)&Elds[seg];
                al[mi] = *(const short8*)&Elds[16 * 528 + seg];
            }
            #pragma unroll
            for (int ni = 0; ni < 2; ++ni) {
                int ntg = kc * 4 + Nh * 2 + ni;
                size_t bidx = ((size_t)ntg * 4 + ds) * 64 + lane;
                short8 bh = Bfrag[bidx];
                short8 bl = Bfrag[16384 + bidx];
                #pragma unroll
                for (int mi = 0; mi < 2; ++mi) {
                    acc[mi][ni] = __builtin_amdgcn_mfma_f32_16x16x32_bf16(al[mi], bh, acc[mi][ni], 0, 0, 0);
                    acc[mi][ni] = __builtin_amdgcn_mfma_f32_16x16x32_bf16(ah[mi], bl, acc[mi][ni], 0, 0, 0);
                    acc[mi][ni] = __builtin_amdgcn_mfma_f32_16x16x32_bf16(ah[mi], bh, acc[mi][ni], 0, 0, 0);
                }
            }
        }
        // fused epilogue for this 64-col chunk (SIGMA-scaled d2; validated math)
        #pragma unroll
        for (int ni = 0; ni < 2; ++ni) {
            int kidx = kc * 64 + Nh * 32 + ni * 16 + mcol;
            float c2v = c2s[kidx];
            #pragma unroll
            for (int mi = 0; mi < 2; ++mi) {
                #pragma unroll
                for (int r = 0; r < 4; ++r) {
                    int s = mi * 4 + r;
                    float d2 = fmaf(NS2, acc[mi][ni][r], e2rs[s] + c2v);
                    uint32_t key = (__float_as_uint(d2) & 0xFFFFFC00u) | (uint32_t)kidx;
                    float dist = __builtin_amdgcn_sqrtf(__builtin_fabsf(d2));
                    sv[s] += EXP2F(-dist);
                    uint32_t k1 = k1v[s];
                    m2v[s] = min(m2v[s], max(k1, key));
                    k1v[s] = min(k1, key);
                }
            }
        }
    }

    // ---- merge across the 16 lanes sharing q (cols) ----
    #pragma unroll
    for (int s = 0; s < 8; ++s) {
        #pragma unroll
        for (int off = 1; off < 16; off <<= 1) {
            uint32_t ok1 = __shfl_xor(k1v[s], off);
            uint32_t om2 = __shfl_xor(m2v[s], off);
            float osv = __shfl_xor(sv[s], off);
            m2v[s] = min(min(m2v[s], om2), max(k1v[s], ok1));
            k1v[s] = min(k1v[s], ok1);
            sv[s] += osv;
        }
    }
    if (mcol == 0) {
        #pragma unroll
        for (int s = 0; s < 8; ++s) {
            int row = (Rh * 2 + (s >> 2)) * 16 + q * 4 + (s & 3);
            mrgk[row * 2 + Nh] = k1v[s];
            mrgm[row * 2 + Nh] = m2v[s];
            mrgs[row * 2 + Nh] = sv[s];
        }
    }
    __syncthreads();

    // ---- final per-row merge across the two col-halves; outputs ----
    if (tid < BM) {
        uint32_t ka = mrgk[tid * 2 + 0], kb = mrgk[tid * 2 + 1];
        uint32_t ma = mrgm[tid * 2 + 0], mb = mrgm[tid * 2 + 1];
        float ss = mrgs[tid * 2 + 0] + mrgs[tid * 2 + 1];
        uint32_t k1 = min(ka, kb);
        uint32_t m2 = min(min(ma, mb), max(ka, kb));
        float m1q = __uint_as_float(k1 & 0xFFFFFC00u);
        float m2q = __uint_as_float(m2 & 0xFFFFFC00u);
        int i1 = (int)(k1 & 1023u);
        // m1q is SIGMA*d2min (quantized); sqrt(SIGMA)*ln2 == 1 recovers dist
        float lossr = logf(ss) + sqrtf(m1q) * LN2;
        out[1 + row0 + tid] = (float)i1;
        if (m2q - m1q < TAUS) {
            int idx = atomicAdd(fcnt, 1);
            if (idx < MAXF) flist[idx] = row0 + tid;
        }
        float v = lossr;
        #pragma unroll
        for (int off = 32; off > 0; off >>= 1) v += __shfl_down(v, off);
        if (tid == 0) atomicAdd(out, v * (1.0f / (float)N_TOTAL));
    }
}

// ---------------------------------------------------------------------------
// refine: exact fp32 recompute (precise sqrt, first-occurrence argmin) for
// flagged rows. EXACT R3/R6-measured version (best tail): RR=8, k-outer loop.
// R4 (RR=16) regressed; R5 (dq-outer) no better. Tie semantics: min by
// (dist, then lower k) == packed u64 min.
// ---------------------------------------------------------------------------
__global__ void refine_kernel(const float* __restrict__ E,
                              const float* __restrict__ C,
                              const float* __restrict__ c2g,
                              const int* __restrict__ fcnt,
                              const int* __restrict__ flist,
                              float* __restrict__ out) {
    int cnt = *fcnt;
    if (cnt > MAXF) cnt = MAXF;
    int base = blockIdx.x * RR;
    if (base >= cnt) return;

    __shared__ float Er[RR][D_DIM];          // 4 KB
    __shared__ float e2r_[RR];
    __shared__ int rowid[RR];
    __shared__ unsigned long long wred[RR][4];

    const int tid = threadIdx.x;
    if (tid < RR) {
        int rr = base + tid;
        if (rr >= cnt) rr = cnt - 1;         // duplicate last row: benign rewrite
        rowid[tid] = flist[rr];
    }
    __syncthreads();
    for (int i = tid; i < RR * 32; i += 256) {
        int rr = i >> 5, dq = i & 31;
        ((float4*)Er[rr])[dq] = ((const float4*)(E + (size_t)rowid[rr] * D_DIM))[dq];
    }
    __syncthreads();
    if (tid < RR) {
        float s = 0.f;
        for (int d = 0; d < D_DIM; ++d) s = fmaf(Er[tid][d], Er[tid][d], s);
        e2r_[tid] = s;
    }
    __syncthreads();

    unsigned long long best[RR];
    #pragma unroll
    for (int r = 0; r < RR; ++r) best[r] = ~0ull;

    for (int ii = 0; ii < 4; ++ii) {
        int k = ii * 256 + tid;
        const float4* C4 = (const float4*)(C + (size_t)k * D_DIM);
        float dot[RR];
        #pragma unroll
        for (int r = 0; r < RR; ++r) dot[r] = 0.f;
        for (int dq = 0; dq < 32; ++dq) {
            float4 cv = C4[dq];
            int d0 = dq * 4;
            #pragma unroll
            for (int r = 0; r < RR; ++r) {
                dot[r] = fmaf(Er[r][d0], cv.x,
                          fmaf(Er[r][d0 + 1], cv.y,
                           fmaf(Er[r][d0 + 2], cv.z,
                            fmaf(Er[r][d0 + 3], cv.w, dot[r]))));
            }
        }
        float c2v = c2g[k];
        #pragma unroll
        for (int r = 0; r < RR; ++r) {
            float d2 = (e2r_[r] + c2v) - 2.f * dot[r];
            float dist = sqrtf(fmaxf(d2, 0.f));
            unsigned long long key =
                (((unsigned long long)__float_as_uint(dist)) << 10) | (unsigned)k;
            best[r] = best[r] < key ? best[r] : key;
        }
    }

    const int wv = tid >> 6;
    #pragma unroll
    for (int r = 0; r < RR; ++r) {
        unsigned long long b = best[r];
        #pragma unroll
        for (int off = 32; off > 0; off >>= 1) {
            unsigned long long o = __shfl_xor(b, off);
            b = o < b ? o : b;
        }
        if ((tid & 63) == 0) wred[r][wv] = b;
    }
    __syncthreads();
    if (tid < RR) {
        unsigned long long b = wred[tid][0];
        #pragma unroll
        for (int j = 1; j < 4; ++j) b = wred[tid][j] < b ? wred[tid][j] : b;
        out[1 + rowid[tid]] = (float)(int)(b & 1023u);
    }
}

extern "C" void kernel_launch(void* const* d_in, const int* in_sizes, int n_in,
                              void* d_out, int out_size, void* d_ws, size_t ws_size,
                              hipStream_t stream) {
    const float* E = (const float*)d_in[0];
    const float* C = (const float*)d_in[1];
    float* out = (float*)d_out;

    unsigned short* Cfrag = (unsigned short*)d_ws;                 // 512 KB
    float* c2 = (float*)((char*)d_ws + 524288);                    // 4 KB
    int* fcnt = (int*)((char*)d_ws + 524288 + 4096);               // 4 B
    int* flist = fcnt + 1;                                         // MAXF ints

    prep_kernel<<<dim3(132), dim3(256), 0, stream>>>(C, Cfrag, c2, out, fcnt);
    fused_mfma_kernel<<<dim3(N_TOTAL / BM), dim3(256), 0, stream>>>(E, Cfrag, c2, out, fcnt, flist);
    refine_kernel<<<dim3(MAXF / RR), dim3(256), 0, stream>>>(E, C, c2, fcnt, flist, out);
}